// Round 1
// baseline (1530.751 us; speedup 1.0000x reference)
//
#include <hip/hip_runtime.h>
#include <math.h>

#define N_RES 256
#define DIM   128
#define NN    (N_RES * N_RES)                 // 65536 rows per batch
static const size_t NNDf = (size_t)NN * DIM;  // 8,388,608 floats per tensor per batch

__device__ __forceinline__ float sigmoidf_(float x) { return 1.f / (1.f + __expf(-x)); }

// ---------------------------------------------------------------------------
// Load 64 rows of X (128 ch each), LayerNorm them, store TRANSPOSED to LDS:
// sXt[k][r], k-stride 68 floats (pad keeps 4-row b128 reads on distinct banks).
// 4 threads per row; row-stat reduce via shfl_xor over the 4-lane group.
// ---------------------------------------------------------------------------
__device__ __forceinline__ void load_ln_t(const float* __restrict__ X, size_t row0,
                                          const float* __restrict__ g,
                                          const float* __restrict__ b,
                                          float* sXt, int t)
{
    int r = t >> 2, part = t & 3;
    const float4* src = (const float4*)(X + (row0 + r) * (size_t)DIM + part * 32);
    float4 vv[8];
    float sum = 0.f, sq = 0.f;
#pragma unroll
    for (int i = 0; i < 8; ++i) {
        float4 v = src[i];
        vv[i] = v;
        sum += v.x + v.y + v.z + v.w;
        sq  += v.x * v.x + v.y * v.y + v.z * v.z + v.w * v.w;
    }
    sum += __shfl_xor(sum, 1); sum += __shfl_xor(sum, 2);
    sq  += __shfl_xor(sq, 1);  sq  += __shfl_xor(sq, 2);
    float m   = sum * (1.f / 128.f);
    float var = sq * (1.f / 128.f) - m * m;
    float rs  = rsqrtf(var + 1e-5f);
#pragma unroll
    for (int i = 0; i < 8; ++i) {
        int c = part * 32 + i * 4;
        float4 v = vv[i];
        sXt[(c + 0) * 68 + r] = (v.x - m) * rs * g[c + 0] + b[c + 0];
        sXt[(c + 1) * 68 + r] = (v.y - m) * rs * g[c + 1] + b[c + 1];
        sXt[(c + 2) * 68 + r] = (v.z - m) * rs * g[c + 2] + b[c + 2];
        sXt[(c + 3) * 68 + r] = (v.w - m) * rs * g[c + 3] + b[c + 3];
    }
}

// Load a 32-output slab of W (row-major [out][k]) transposed into sWt[k][o],
// k-stride 36 floats.
__device__ __forceinline__ void load_w_t(const float* __restrict__ W, int o0,
                                         float* sWt, int t)
{
    int o_l = t >> 3;            // 0..31
    int kp  = (t & 7) * 16;      // 16 consecutive k per thread
    const float4* src = (const float4*)(W + (size_t)(o0 + o_l) * DIM + kp);
#pragma unroll
    for (int i = 0; i < 4; ++i) {
        float4 v = src[i];
        int k = kp + i * 4;
        sWt[(k + 0) * 36 + o_l] = v.x;
        sWt[(k + 1) * 36 + o_l] = v.y;
        sWt[(k + 2) * 36 + o_l] = v.z;
        sWt[(k + 3) * 36 + o_l] = v.w;
    }
}

// 64-row x 32-out slab GEMM from transposed LDS tiles. Per thread: 4 rows x 2 outs.
__device__ __forceinline__ void matmul_slab(const float* sXt, const float* sWt,
                                            int tr, int tc, float acc[4][2])
{
#pragma unroll 8
    for (int k = 0; k < 128; ++k) {
        float4 a4 = *(const float4*)&sXt[k * 68 + tr * 4];
        float2 w2 = *(const float2*)&sWt[k * 36 + tc * 2];
        acc[0][0] += a4.x * w2.x; acc[0][1] += a4.x * w2.y;
        acc[1][0] += a4.y * w2.x; acc[1][1] += a4.y * w2.y;
        acc[2][0] += a4.z * w2.x; acc[2][1] += a4.z * w2.y;
        acc[3][0] += a4.w * w2.x; acc[3][1] += a4.w * w2.y;
    }
}

// ---------------------------------------------------------------------------
// K1: zl = LN(z); a = sig(zl@wga^T+bga)*(zl@wpa^T+bpa); bb likewise.
// 64 rows per block. Outputs are chunk-local [nbc][N][N][D].
// ---------------------------------------------------------------------------
__global__ __launch_bounds__(256, 2) void k_lin(
    const float* __restrict__ z,
    const float* __restrict__ g_in, const float* __restrict__ b_in,
    const float* __restrict__ wpa, const float* __restrict__ bpa,
    const float* __restrict__ wga, const float* __restrict__ bga,
    const float* __restrict__ wpb, const float* __restrict__ bpb,
    const float* __restrict__ wgb, const float* __restrict__ bgb,
    float* __restrict__ a_out, float* __restrict__ b_out, int b0)
{
    __shared__ float sXt[128 * 68];   // 34.8 KB
    __shared__ float sWt[128 * 36];   // 18.4 KB
    int t = threadIdx.x;
    size_t lrow0 = (size_t)blockIdx.x * 64;          // chunk-local row base
    size_t zrow0 = (size_t)b0 * NN + lrow0;          // absolute z row base

    load_ln_t(z, zrow0, g_in, b_in, sXt, t);

    int tr = t >> 4;   // 0..15 -> rows tr*4..tr*4+3
    int tc = t & 15;   // 0..15 -> outs tc*2..tc*2+1

    for (int pair = 0; pair < 2; ++pair) {
        const float* Wg = pair ? wgb : wga;
        const float* Bg = pair ? bgb : bga;
        const float* Wp = pair ? wpb : wpa;
        const float* Bp = pair ? bpb : bpa;
        float* op = pair ? b_out : a_out;
        for (int slab = 0; slab < 4; ++slab) {
            int o0 = slab * 32;
            __syncthreads();
            load_w_t(Wg, o0, sWt, t);
            __syncthreads();
            float ga[4][2];
#pragma unroll
            for (int ii = 0; ii < 4; ++ii) { ga[ii][0] = Bg[o0 + tc * 2]; ga[ii][1] = Bg[o0 + tc * 2 + 1]; }
            matmul_slab(sXt, sWt, tr, tc, ga);
            __syncthreads();
            load_w_t(Wp, o0, sWt, t);
            __syncthreads();
            float pa[4][2];
#pragma unroll
            for (int ii = 0; ii < 4; ++ii) { pa[ii][0] = Bp[o0 + tc * 2]; pa[ii][1] = Bp[o0 + tc * 2 + 1]; }
            matmul_slab(sXt, sWt, tr, tc, pa);
#pragma unroll
            for (int ii = 0; ii < 4; ++ii) {
                float2 o;
                o.x = pa[ii][0] * sigmoidf_(ga[ii][0]);
                o.y = pa[ii][1] * sigmoidf_(ga[ii][1]);
                *(float2*)&op[(lrow0 + tr * 4 + ii) * (size_t)DIM + o0 + tc * 2] = o;
            }
        }
    }
}

// ---------------------------------------------------------------------------
// K2: tri[b,i,j,d] = sum_k a[b,i,k,d] * bb[b,j,k,d]
// Block tile: 32 i x 32 j x 16 d, K staged 8 at a time in LDS.
// Per thread: 4i x 4j x 4d accumulators (64 fp32). All chunk-local.
// ---------------------------------------------------------------------------
__global__ __launch_bounds__(256, 2) void k_tri(
    const float* __restrict__ a, const float* __restrict__ b,
    float* __restrict__ tri)
{
    __shared__ float sA[32 * 132];   // [i][k(8)][d(16)] +4 pad, 16.9 KB
    __shared__ float sB[32 * 132];
    int t = threadIdx.x;
    int b_l  = blockIdx.x >> 6;
    int tile = blockIdx.x & 63;
    int it = tile >> 3, jt = tile & 7;
    int d0 = blockIdx.y * 16;

    int dg = t & 3;          // d sub-quad  -> d0 + dg*4
    int ig = (t >> 2) & 7;   // i group     -> ig*4
    int jg = t >> 5;         // j group     -> jg*4

    int p = t >> 2, f = t & 3;
    int kl = p & 7, ih = p >> 3;   // staging coords

    float4 acc[4][4];
#pragma unroll
    for (int ii = 0; ii < 4; ++ii)
#pragma unroll
        for (int jj = 0; jj < 4; ++jj) acc[ii][jj] = make_float4(0.f, 0.f, 0.f, 0.f);

    size_t abase = ((size_t)b_l * NN + (size_t)(it * 32) * N_RES) * DIM;
    size_t bbase = ((size_t)b_l * NN + (size_t)(jt * 32) * N_RES) * DIM;

    for (int k0 = 0; k0 < N_RES; k0 += 8) {
        __syncthreads();
#pragma unroll
        for (int itr = 0; itr < 4; ++itr) {
            int il = itr * 8 + ih;
            size_t goff = (size_t)il * N_RES * DIM + (size_t)(k0 + kl) * DIM + d0 + f * 4;
            *(float4*)&sA[il * 132 + kl * 16 + f * 4] = *(const float4*)&a[abase + goff];
            *(float4*)&sB[il * 132 + kl * 16 + f * 4] = *(const float4*)&b[bbase + goff];
        }
        __syncthreads();
#pragma unroll
        for (int k = 0; k < 8; ++k) {
            float4 av[4], bv[4];
#pragma unroll
            for (int ii = 0; ii < 4; ++ii) av[ii] = *(const float4*)&sA[(ig * 4 + ii) * 132 + k * 16 + dg * 4];
#pragma unroll
            for (int jj = 0; jj < 4; ++jj) bv[jj] = *(const float4*)&sB[(jg * 4 + jj) * 132 + k * 16 + dg * 4];
#pragma unroll
            for (int ii = 0; ii < 4; ++ii)
#pragma unroll
                for (int jj = 0; jj < 4; ++jj) {
                    acc[ii][jj].x += av[ii].x * bv[jj].x;
                    acc[ii][jj].y += av[ii].y * bv[jj].y;
                    acc[ii][jj].z += av[ii].z * bv[jj].z;
                    acc[ii][jj].w += av[ii].w * bv[jj].w;
                }
        }
    }

    size_t obase = (size_t)b_l * NN;
#pragma unroll
    for (int ii = 0; ii < 4; ++ii)
#pragma unroll
        for (int jj = 0; jj < 4; ++jj) {
            int i_g = it * 32 + ig * 4 + ii;
            int j_g = jt * 32 + jg * 4 + jj;
            *(float4*)&tri[(obase + (size_t)i_g * N_RES + j_g) * DIM + d0 + dg * 4] = acc[ii][jj];
        }
}

// ---------------------------------------------------------------------------
// K3: out = sig(LN(z)@wog^T+bog) * (LN(tri,g_out,b_out)@wop^T+bop)
// 64 rows per block; gate accumulators held in regs across the sXt reuse.
// ---------------------------------------------------------------------------
__global__ __launch_bounds__(256, 2) void k_out(
    const float* __restrict__ tri, const float* __restrict__ z,
    const float* __restrict__ g_in, const float* __restrict__ b_in,
    const float* __restrict__ g_out, const float* __restrict__ b_out,
    const float* __restrict__ wop, const float* __restrict__ bop,
    const float* __restrict__ wog, const float* __restrict__ bog,
    float* __restrict__ out, int b0)
{
    __shared__ float sXt[128 * 68];
    __shared__ float sWt[128 * 36];
    int t = threadIdx.x;
    size_t lrow0 = (size_t)blockIdx.x * 64;
    size_t zrow0 = (size_t)b0 * NN + lrow0;
    int tr = t >> 4, tc = t & 15;

    // Phase A: gate = zl @ wog^T + bog (held in regs)
    load_ln_t(z, zrow0, g_in, b_in, sXt, t);
    float gate[4][4][2];
#pragma unroll
    for (int slab = 0; slab < 4; ++slab) {
        int o0 = slab * 32;
        __syncthreads();
        load_w_t(wog, o0, sWt, t);
        __syncthreads();
        float acc[4][2];
#pragma unroll
        for (int ii = 0; ii < 4; ++ii) { acc[ii][0] = bog[o0 + tc * 2]; acc[ii][1] = bog[o0 + tc * 2 + 1]; }
        matmul_slab(sXt, sWt, tr, tc, acc);
#pragma unroll
        for (int ii = 0; ii < 4; ++ii) { gate[slab][ii][0] = acc[ii][0]; gate[slab][ii][1] = acc[ii][1]; }
    }

    // Phase B: reuse sXt for LN(tri)
    __syncthreads();
    load_ln_t(tri, lrow0, g_out, b_out, sXt, t);
#pragma unroll
    for (int slab = 0; slab < 4; ++slab) {
        int o0 = slab * 32;
        __syncthreads();
        load_w_t(wop, o0, sWt, t);
        __syncthreads();
        float acc[4][2];
#pragma unroll
        for (int ii = 0; ii < 4; ++ii) { acc[ii][0] = bop[o0 + tc * 2]; acc[ii][1] = bop[o0 + tc * 2 + 1]; }
        matmul_slab(sXt, sWt, tr, tc, acc);
#pragma unroll
        for (int ii = 0; ii < 4; ++ii) {
            float2 o;
            o.x = acc[ii][0] * sigmoidf_(gate[slab][ii][0]);
            o.y = acc[ii][1] * sigmoidf_(gate[slab][ii][1]);
            *(float2*)&out[(zrow0 + tr * 4 + ii) * (size_t)DIM + o0 + tc * 2] = o;
        }
    }
}

extern "C" void kernel_launch(void* const* d_in, const int* in_sizes, int n_in,
                              void* d_out, int out_size, void* d_ws, size_t ws_size,
                              hipStream_t stream)
{
    const float* z    = (const float*)d_in[0];
    const float* g_in = (const float*)d_in[1];
    const float* b_in = (const float*)d_in[2];
    const float* wpa  = (const float*)d_in[3];
    const float* bpa  = (const float*)d_in[4];
    const float* wga  = (const float*)d_in[5];
    const float* bga  = (const float*)d_in[6];
    const float* wpb  = (const float*)d_in[7];
    const float* bpb  = (const float*)d_in[8];
    const float* wgb  = (const float*)d_in[9];
    const float* bgb  = (const float*)d_in[10];
    const float* gout = (const float*)d_in[11];
    const float* bout = (const float*)d_in[12];
    const float* wop  = (const float*)d_in[13];
    const float* bop  = (const float*)d_in[14];
    const float* wog  = (const float*)d_in[15];
    const float* bog  = (const float*)d_in[16];
    float* out = (float*)d_out;
    float* ws  = (float*)d_ws;

    // Per-batch scratch: a, bb, tri (fp32) = 3 * 33.55 MB = 100.7 MB.
    // Chunk batches so scratch fits ws_size (deterministic given ws_size).
    const size_t per_batch_bytes = 3 * NNDf * sizeof(float);
    int nb = (int)(ws_size / per_batch_bytes);
    if (nb < 1) nb = 1;
    if (nb > 4) nb = 4;
    float* aw = ws;
    float* bw = ws + (size_t)nb * NNDf;
    float* tw = ws + 2 * (size_t)nb * NNDf;

    for (int b0 = 0; b0 < 4; b0 += nb) {
        int nbc = (4 - b0) < nb ? (4 - b0) : nb;
        k_lin<<<nbc * 1024, 256, 0, stream>>>(z, g_in, b_in, wpa, bpa, wga, bga,
                                              wpb, bpb, wgb, bgb, aw, bw, b0);
        k_tri<<<dim3(nbc * 64, 8), 256, 0, stream>>>(aw, bw, tw);
        k_out<<<nbc * 1024, 256, 0, stream>>>(tw, z, g_in, b_in, gout, bout,
                                              wop, bop, wog, bog, out, b0);
    }
}